// Round 1
// baseline (4450.088 us; speedup 1.0000x reference)
//
#include <hip/hip_runtime.h>
#include <hip/hip_bf16.h>
#include <cstdint>

#define HIDDEN 4096
#define NH 32
#define NKV 8
#define HD 128
#define SEQ 2048
#define BSZ 2

using bf16x8 = __attribute__((ext_vector_type(8))) short;
using f32x4  = __attribute__((ext_vector_type(4))) float;

__device__ __forceinline__ ushort f2bf(float f) {
  union { float f; uint32_t u; } v; v.f = f;
  uint32_t r = (v.u + 0x7FFFu + ((v.u >> 16) & 1u)) >> 16;  // RNE
  return (ushort)r;
}
__device__ __forceinline__ float bf2f(ushort s) {
  union { uint32_t u; float f; } v; v.u = ((uint32_t)s) << 16;
  return v.f;
}

// ---------------------------------------------------------------------------
// GEMM: C[MxN] = A[MxK] * B[KxN], A row-major (fp32 or bf16), B row-major fp32.
// 128x128 tile, BK=64, 4 waves (2x2), each wave 64x64 via 4x4 16x16x32 MFMAs.
// ---------------------------------------------------------------------------
template<int A_BF16, int OUT_BF16>
__global__ __launch_bounds__(256)
void gemm_kernel(const void* __restrict__ Ap, const float* __restrict__ B,
                 void* __restrict__ Cp, int M, int N, int K) {
  __shared__ ushort As[128][72];   // [m][k], row = 144B (2-way bank alias, free)
  __shared__ ushort Bs[128][72];   // [n][k] (B transposed into LDS)
  const int tid  = threadIdx.x;
  const int lane = tid & 63;
  const int wave = tid >> 6;
  const int l15 = lane & 15, l4 = lane >> 4;
  const int wr = (wave >> 1) * 64, wc = (wave & 1) * 64;
  const int m0 = blockIdx.y * 128, n0 = blockIdx.x * 128;

  f32x4 acc[4][4] = {};

  for (int k0 = 0; k0 < K; k0 += 64) {
    // ---- stage A tile (128x64) as bf16 ----
    if (A_BF16) {
      const ushort* A = (const ushort*)Ap;
      for (int i = 0; i < 4; ++i) {
        int idx = i * 256 + tid;
        int r = idx >> 3, c = (idx & 7) * 8;
        const ushort* src = A + (size_t)(m0 + r) * K + k0 + c;
        *(bf16x8*)&As[r][c] = *(const bf16x8*)src;
      }
    } else {
      const float* A = (const float*)Ap;
      for (int i = 0; i < 8; ++i) {
        int idx = i * 256 + tid;
        int r = idx >> 4, c = (idx & 15) * 4;
        const float4 v = *(const float4*)(A + (size_t)(m0 + r) * K + k0 + c);
        uint2 p;
        p.x = (uint)f2bf(v.x) | ((uint)f2bf(v.y) << 16);
        p.y = (uint)f2bf(v.z) | ((uint)f2bf(v.w) << 16);
        *(uint2*)&As[r][c] = p;
      }
    }
    // ---- stage B tile (64x128) transposed -> Bs[n][k] ----
    for (int i = 0; i < 16; ++i) {
      int idx = i * 256 + tid;
      int n = idx & 127, k = (idx >> 7) * 2;
      const float* bp = B + (size_t)(k0 + k) * N + n0 + n;
      uint p = (uint)f2bf(bp[0]) | ((uint)f2bf(bp[N]) << 16);
      *(uint*)&Bs[n][k] = p;
    }
    __syncthreads();
    // ---- MFMA ----
    for (int kk = 0; kk < 2; ++kk) {
      const int ko = kk * 32 + l4 * 8;
      bf16x8 a[4], b[4];
      for (int mi = 0; mi < 4; ++mi)
        a[mi] = *(const bf16x8*)&As[wr + mi * 16 + l15][ko];
      for (int ni = 0; ni < 4; ++ni)
        b[ni] = *(const bf16x8*)&Bs[wc + ni * 16 + l15][ko];
      for (int mi = 0; mi < 4; ++mi)
        for (int ni = 0; ni < 4; ++ni)
          acc[mi][ni] = __builtin_amdgcn_mfma_f32_16x16x32_bf16(a[mi], b[ni], acc[mi][ni], 0, 0, 0);
    }
    __syncthreads();
  }
  // ---- epilogue: D row=(lane>>4)*4+r, col=lane&15 ----
  for (int mi = 0; mi < 4; ++mi)
    for (int ni = 0; ni < 4; ++ni)
      for (int r = 0; r < 4; ++r) {
        int row = m0 + wr + mi * 16 + l4 * 4 + r;
        int col = n0 + wc + ni * 16 + l15;
        float val = acc[mi][ni][r];
        if (OUT_BF16) ((ushort*)Cp)[(size_t)row * N + col] = f2bf(val);
        else          ((float*)Cp)[(size_t)row * N + col]  = val;
      }
}

// ---------------------------------------------------------------------------
// RoPE in place on bf16 buffer laid out (b, s, nh*128). Thread owns pair (j, j+64).
// ---------------------------------------------------------------------------
__global__ __launch_bounds__(256)
void rope_kernel(ushort* buf, const int* __restrict__ pos_ids, int nh, int total) {
  int t = blockIdx.x * 256 + threadIdx.x;
  if (t >= total) return;
  int j = t & 63;
  int rest = t >> 6;
  int h = rest % nh;
  int bs = rest / nh;                 // b*SEQ + s
  float pos = (float)pos_ids[bs];
  // inv_freq = 10000^(-j/64) = 2^(-j/64 * log2(10000))
  float inv = exp2f(-(float)j * (13.287712379549449f / 64.0f));
  float ang = pos * inv;
  float c = cosf(ang), s = sinf(ang);
  ushort* p = buf + ((size_t)bs * nh + h) * HD + j;
  float x1 = bf2f(p[0]), x2 = bf2f(p[64]);
  p[0]  = f2bf(x1 * c - x2 * s);
  p[64] = f2bf(x2 * c + x1 * s);
}

// ---------------------------------------------------------------------------
// Flash attention, causal. Block = (qtile of 64, head, batch). 4 waves x 16 q-rows.
// Q,K raw layout (b, s, nh*128) bf16 (RoPE'd); V raw (b, s, 1024) bf16.
// AO out (b, s, 4096) bf16.
// ---------------------------------------------------------------------------
__global__ __launch_bounds__(256)
void attn_kernel(const ushort* __restrict__ Q, const ushort* __restrict__ K,
                 const ushort* __restrict__ V, ushort* __restrict__ AO) {
  const int b = blockIdx.z, h = blockIdx.y, kh = h >> 2;
  const int q0 = blockIdx.x * 64;
  const int tid = threadIdx.x, lane = tid & 63, wave = tid >> 6;
  const int l15 = lane & 15, l4 = lane >> 4;
  const float scale = 0.08838834764831845f;  // 1/sqrt(128)

  __shared__ ushort Vt[128][72];       // Vt[d][k], transposed V tile
  __shared__ ushort Ps[4][16][72];     // per-wave P tile 16x64

  // Q fragments (A-operand), held for the whole block
  bf16x8 qf[4];
  {
    const ushort* qp = Q + ((size_t)(b * SEQ) + q0 + wave * 16 + l15) * HIDDEN
                         + h * HD + l4 * 8;
    for (int kk = 0; kk < 4; ++kk) qf[kk] = *(const bf16x8*)(qp + kk * 32);
  }

  float m[4], l[4];
  for (int r = 0; r < 4; ++r) { m[r] = -1e30f; l[r] = 0.0f; }
  f32x4 accO[8] = {};

  const int nt = blockIdx.x + 1;  // causal: key tiles with k0 <= q0
  for (int t = 0; t < nt; ++t) {
    const int k0 = t * 64;
    // ---- stage V tile transposed: Vt[d][k] ----
    for (int i = 0; i < 16; ++i) {
      int idx = i * 256 + tid;
      int d = idx & 127, k = (idx >> 7) * 2;
      const ushort* vp = V + ((size_t)(b * SEQ) + k0 + k) * (NKV * HD) + kh * HD + d;
      uint pk = (uint)vp[0] | ((uint)vp[NKV * HD] << 16);
      *(uint*)&Vt[d][k] = pk;
    }
    __syncthreads();
    // ---- QK^T: S[16 q x 64 k] per wave ----
    f32x4 accS[4] = {};
    for (int kk = 0; kk < 4; ++kk) {
      const ushort* kp = K + ((size_t)(b * SEQ) + k0 + l15) * (NKV * HD)
                           + kh * HD + l4 * 8 + kk * 32;
      for (int c = 0; c < 4; ++c) {
        bf16x8 bfr = *(const bf16x8*)(kp + (size_t)c * 16 * (NKV * HD));
        accS[c] = __builtin_amdgcn_mfma_f32_16x16x32_bf16(qf[kk], bfr, accS[c], 0, 0, 0);
      }
    }
    // ---- online softmax ----
    float pvv[4][4];
    float pmax[4], rsum[4];
    for (int r = 0; r < 4; ++r) {
      int qq = q0 + wave * 16 + l4 * 4 + r;
      float mx = -1e30f;
      for (int c = 0; c < 4; ++c) {
        int kq = k0 + c * 16 + l15;
        float x = accS[c][r] * scale;
        if (kq > qq) x -= 1e9f;
        pvv[c][r] = x;
        mx = fmaxf(mx, x);
      }
      pmax[r] = mx;
    }
    for (int d = 1; d < 16; d <<= 1)
      for (int r = 0; r < 4; ++r) pmax[r] = fmaxf(pmax[r], __shfl_xor(pmax[r], d));
    for (int r = 0; r < 4; ++r) {
      float mn = fmaxf(m[r], pmax[r]);
      float alpha = __expf(m[r] - mn);
      m[r] = mn;
      float s = 0.0f;
      for (int c = 0; c < 4; ++c) {
        float p = __expf(pvv[c][r] - mn);
        pvv[c][r] = p;
        s += p;
      }
      rsum[r] = s;
      l[r] *= alpha;
      for (int db = 0; db < 8; ++db) accO[db][r] *= alpha;
    }
    for (int d = 1; d < 16; d <<= 1)
      for (int r = 0; r < 4; ++r) rsum[r] += __shfl_xor(rsum[r], d);
    for (int r = 0; r < 4; ++r) l[r] += rsum[r];
    // ---- write P (bf16) to wave-local LDS tile ----
    for (int c = 0; c < 4; ++c)
      for (int r = 0; r < 4; ++r)
        Ps[wave][l4 * 4 + r][c * 16 + l15] = f2bf(pvv[c][r]);
    // ---- PV: O += P(16x64) * V(64x128) ----
    for (int kk = 0; kk < 2; ++kk) {
      bf16x8 pa = *(const bf16x8*)&Ps[wave][l15][kk * 32 + l4 * 8];
      for (int db = 0; db < 8; ++db) {
        bf16x8 vb = *(const bf16x8*)&Vt[db * 16 + l15][kk * 32 + l4 * 8];
        accO[db] = __builtin_amdgcn_mfma_f32_16x16x32_bf16(pa, vb, accO[db], 0, 0, 0);
      }
    }
    __syncthreads();
  }
  // ---- epilogue: divide by l, write AO[b][q][h*128+d] ----
  for (int db = 0; db < 8; ++db)
    for (int r = 0; r < 4; ++r) {
      int q = q0 + wave * 16 + l4 * 4 + r;
      int col = h * HD + db * 16 + l15;
      AO[((size_t)(b * SEQ) + q) * HIDDEN + col] = f2bf(accO[db][r] / l[r]);
    }
}

// ---------------------------------------------------------------------------
extern "C" void kernel_launch(void* const* d_in, const int* in_sizes, int n_in,
                              void* d_out, int out_size, void* d_ws, size_t ws_size,
                              hipStream_t stream) {
  (void)in_sizes; (void)n_in; (void)out_size; (void)ws_size;
  const float* X   = (const float*)d_in[0];
  // d_in[1] = attention_mask (exact causal * -1e9; applied analytically)
  const int*   pos = (const int*)d_in[2];
  const float* Wq  = (const float*)d_in[3];
  const float* Wk  = (const float*)d_in[4];
  const float* Wv  = (const float*)d_in[5];
  const float* Wo  = (const float*)d_in[6];

  char* ws = (char*)d_ws;
  ushort* Qraw = (ushort*)(ws);                    // B*S*4096 bf16 = 33,554,432 B
  ushort* Kraw = (ushort*)(ws + 33554432);         // B*S*1024 bf16 =  8,388,608 B
  ushort* Vraw = (ushort*)(ws + 41943040);         // B*S*1024 bf16 =  8,388,608 B
  ushort* AO   = (ushort*)(ws + 50331648);         // B*S*4096 bf16 = 33,554,432 B

  const int M = BSZ * SEQ;  // 4096
  dim3 blk(256);

  // projections (bf16 MFMA, fp32 inputs converted during staging)
  gemm_kernel<0, 1><<<dim3(HIDDEN / 128, M / 128), blk, 0, stream>>>(X, Wq, Qraw, M, HIDDEN, HIDDEN);
  gemm_kernel<0, 1><<<dim3((NKV * HD) / 128, M / 128), blk, 0, stream>>>(X, Wk, Kraw, M, NKV * HD, HIDDEN);
  gemm_kernel<0, 1><<<dim3((NKV * HD) / 128, M / 128), blk, 0, stream>>>(X, Wv, Vraw, M, NKV * HD, HIDDEN);

  // RoPE in place
  rope_kernel<<<dim3((M * NH * 64) / 256), blk, 0, stream>>>(Qraw, pos, NH, M * NH * 64);
  rope_kernel<<<dim3((M * NKV * 64) / 256), blk, 0, stream>>>(Kraw, pos, NKV, M * NKV * 64);

  // flash attention
  attn_kernel<<<dim3(SEQ / 64, NH, BSZ), blk, 0, stream>>>(Qraw, Kraw, Vraw, AO);

  // output projection -> fp32 d_out
  gemm_kernel<1, 0><<<dim3(HIDDEN / 128, M / 128), blk, 0, stream>>>(AO, Wo, d_out, M, HIDDEN, HIDDEN);
}

// Round 2
// 1222.519 us; speedup vs baseline: 3.6401x; 3.6401x over previous
//
#include <hip/hip_runtime.h>
#include <hip/hip_bf16.h>
#include <cstdint>

#define HIDDEN 4096
#define NH 32
#define NKV 8
#define HD 128
#define SEQ 2048
#define BSZ 2

using bf16x8 = __attribute__((ext_vector_type(8))) short;
using f32x4  = __attribute__((ext_vector_type(4))) float;

__device__ __forceinline__ ushort f2bf(float f) {
  union { float f; uint32_t u; } v; v.f = f;
  uint32_t r = (v.u + 0x7FFFu + ((v.u >> 16) & 1u)) >> 16;  // RNE
  return (ushort)r;
}
__device__ __forceinline__ float bf2f(ushort s) {
  union { uint32_t u; float f; } v; v.u = ((uint32_t)s) << 16;
  return v.f;
}

__device__ __forceinline__ void gload_lds16(const void* g, void* l) {
  __builtin_amdgcn_global_load_lds(
      (const __attribute__((address_space(1))) void*)g,
      (__attribute__((address_space(3))) void*)l, 16, 0, 0);
}

// ---------------------------------------------------------------------------
// fp32 -> bf16 elementwise convert (vectorized, 8 elems/thread)
// ---------------------------------------------------------------------------
__global__ __launch_bounds__(256)
void cvt_bf16_kernel(const float* __restrict__ X, ushort* __restrict__ Xb, int n8) {
  int t = blockIdx.x * 256 + threadIdx.x;
  if (t >= n8) return;
  size_t i = (size_t)t * 8;
  float4 a = *(const float4*)(X + i);
  float4 b = *(const float4*)(X + i + 4);
  uint4 p;
  p.x = (uint)f2bf(a.x) | ((uint)f2bf(a.y) << 16);
  p.y = (uint)f2bf(a.z) | ((uint)f2bf(a.w) << 16);
  p.z = (uint)f2bf(b.x) | ((uint)f2bf(b.y) << 16);
  p.w = (uint)f2bf(b.z) | ((uint)f2bf(b.w) << 16);
  *(uint4*)(Xb + i) = p;
}

// ---------------------------------------------------------------------------
// W[K][N] fp32 -> WT[N][K] bf16 (32x32 LDS tile transpose)
// ---------------------------------------------------------------------------
__global__ __launch_bounds__(256)
void transpose_bf16_kernel(const float* __restrict__ W, ushort* __restrict__ WT,
                           int K, int N) {
  __shared__ ushort tile[32][33];
  const int k0 = blockIdx.y * 32, n0 = blockIdx.x * 32;
  const int tx = threadIdx.x & 31, ty = threadIdx.x >> 5;  // ty 0..7
  for (int i = 0; i < 4; ++i) {
    int k = ty + i * 8;
    tile[k][tx] = f2bf(W[(size_t)(k0 + k) * N + n0 + tx]);
  }
  __syncthreads();
  for (int i = 0; i < 4; ++i) {
    int n = ty + i * 8;
    WT[(size_t)(n0 + n) * K + k0 + tx] = tile[tx][n];
  }
}

// ---------------------------------------------------------------------------
// GEMM (m97 structure): C[MxN] = A[MxK] * BT[NxK]^T, A/BT bf16 row-major.
// 128x128 tile, BK=64, 4 waves (2x2), global_load_lds width-16 staging,
// linear LDS, ds_read_b128 fragments, 32 MFMAs / K-step.
// ---------------------------------------------------------------------------
template<int OUT_BF16>
__global__ __launch_bounds__(256)
void gemm_bf16_kernel(const ushort* __restrict__ A, const ushort* __restrict__ BT,
                      void* __restrict__ Cp, int M, int N, int K) {
  __shared__ ushort As[128 * 64];
  __shared__ ushort Bs[128 * 64];
  const int tid = threadIdx.x;
  const int lane = tid & 63, wave = tid >> 6;
  const int l15 = lane & 15, l4 = lane >> 4;
  const int wr = (wave >> 1) * 64, wc = (wave & 1) * 64;
  const int m0 = blockIdx.y * 128, n0 = blockIdx.x * 128;

  // staging geometry: 16 chunks of 1024B per operand tile; 4 chunks/wave.
  // within a chunk, lane covers row (lane>>3), elem col (lane&7)*8.
  const int srow = lane >> 3;
  const int scol = (lane & 7) * 8;

  f32x4 acc[4][4] = {};

  for (int k0 = 0; k0 < K; k0 += 64) {
#pragma unroll
    for (int c = 0; c < 4; ++c) {
      const int chunk = wave * 4 + c;          // 0..15
      const int row = chunk * 8 + srow;        // 0..127
      gload_lds16(A  + (size_t)(m0 + row) * K + k0 + scol, &As[chunk * 512 + lane * 8]);
      gload_lds16(BT + (size_t)(n0 + row) * K + k0 + scol, &Bs[chunk * 512 + lane * 8]);
    }
    __syncthreads();
#pragma unroll
    for (int kk = 0; kk < 2; ++kk) {
      const int ko = kk * 32 + l4 * 8;
      bf16x8 a[4], b[4];
#pragma unroll
      for (int mi = 0; mi < 4; ++mi)
        a[mi] = *(const bf16x8*)&As[(wr + mi * 16 + l15) * 64 + ko];
#pragma unroll
      for (int ni = 0; ni < 4; ++ni)
        b[ni] = *(const bf16x8*)&Bs[(wc + ni * 16 + l15) * 64 + ko];
#pragma unroll
      for (int mi = 0; mi < 4; ++mi)
#pragma unroll
        for (int ni = 0; ni < 4; ++ni)
          acc[mi][ni] = __builtin_amdgcn_mfma_f32_16x16x32_bf16(a[mi], b[ni], acc[mi][ni], 0, 0, 0);
    }
    __syncthreads();
  }
  // epilogue: D row=(lane>>4)*4+r, col=lane&15
#pragma unroll
  for (int mi = 0; mi < 4; ++mi)
#pragma unroll
    for (int ni = 0; ni < 4; ++ni)
#pragma unroll
      for (int r = 0; r < 4; ++r) {
        int row = m0 + wr + mi * 16 + l4 * 4 + r;
        int col = n0 + wc + ni * 16 + l15;
        float val = acc[mi][ni][r];
        if (OUT_BF16) ((ushort*)Cp)[(size_t)row * N + col] = f2bf(val);
        else          ((float*)Cp)[(size_t)row * N + col]  = val;
      }
}

// ---------------------------------------------------------------------------
// RoPE in place on bf16 buffer laid out (b, s, nh*128). Thread owns pair (j, j+64).
// ---------------------------------------------------------------------------
__global__ __launch_bounds__(256)
void rope_kernel(ushort* buf, const int* __restrict__ pos_ids, int nh, int total) {
  int t = blockIdx.x * 256 + threadIdx.x;
  if (t >= total) return;
  int j = t & 63;
  int rest = t >> 6;
  int h = rest % nh;
  int bs = rest / nh;                 // b*SEQ + s
  float pos = (float)pos_ids[bs];
  float inv = exp2f(-(float)j * (13.287712379549449f / 64.0f));
  float ang = pos * inv;
  float c = cosf(ang), s = sinf(ang);
  ushort* p = buf + ((size_t)bs * nh + h) * HD + j;
  float x1 = bf2f(p[0]), x2 = bf2f(p[64]);
  p[0]  = f2bf(x1 * c - x2 * s);
  p[64] = f2bf(x2 * c + x1 * s);
}

// ---------------------------------------------------------------------------
// Flash attention, causal. Block = (qtile of 64, head, batch). 4 waves x 16 q-rows.
// ---------------------------------------------------------------------------
__global__ __launch_bounds__(256)
void attn_kernel(const ushort* __restrict__ Q, const ushort* __restrict__ K,
                 const ushort* __restrict__ V, ushort* __restrict__ AO) {
  const int b = blockIdx.z, h = blockIdx.y, kh = h >> 2;
  const int q0 = blockIdx.x * 64;
  const int tid = threadIdx.x, lane = tid & 63, wave = tid >> 6;
  const int l15 = lane & 15, l4 = lane >> 4;
  const float scale = 0.08838834764831845f;  // 1/sqrt(128)

  __shared__ ushort Vt[128][72];       // Vt[d][k], transposed V tile
  __shared__ ushort Ps[4][16][72];     // per-wave P tile 16x64

  bf16x8 qf[4];
  {
    const ushort* qp = Q + ((size_t)(b * SEQ) + q0 + wave * 16 + l15) * HIDDEN
                         + h * HD + l4 * 8;
    for (int kk = 0; kk < 4; ++kk) qf[kk] = *(const bf16x8*)(qp + kk * 32);
  }

  float m[4], l[4];
  for (int r = 0; r < 4; ++r) { m[r] = -1e30f; l[r] = 0.0f; }
  f32x4 accO[8] = {};

  const int nt = blockIdx.x + 1;  // causal
  for (int t = 0; t < nt; ++t) {
    const int k0 = t * 64;
    for (int i = 0; i < 16; ++i) {
      int idx = i * 256 + tid;
      int d = idx & 127, k = (idx >> 7) * 2;
      const ushort* vp = V + ((size_t)(b * SEQ) + k0 + k) * (NKV * HD) + kh * HD + d;
      uint pk = (uint)vp[0] | ((uint)vp[NKV * HD] << 16);
      *(uint*)&Vt[d][k] = pk;
    }
    __syncthreads();
    f32x4 accS[4] = {};
    for (int kk = 0; kk < 4; ++kk) {
      const ushort* kp = K + ((size_t)(b * SEQ) + k0 + l15) * (NKV * HD)
                           + kh * HD + l4 * 8 + kk * 32;
      for (int c = 0; c < 4; ++c) {
        bf16x8 bfr = *(const bf16x8*)(kp + (size_t)c * 16 * (NKV * HD));
        accS[c] = __builtin_amdgcn_mfma_f32_16x16x32_bf16(qf[kk], bfr, accS[c], 0, 0, 0);
      }
    }
    float pvv[4][4];
    float pmax[4], rsum[4];
    for (int r = 0; r < 4; ++r) {
      int qq = q0 + wave * 16 + l4 * 4 + r;
      float mx = -1e30f;
      for (int c = 0; c < 4; ++c) {
        int kq = k0 + c * 16 + l15;
        float x = accS[c][r] * scale;
        if (kq > qq) x -= 1e9f;
        pvv[c][r] = x;
        mx = fmaxf(mx, x);
      }
      pmax[r] = mx;
    }
    for (int d = 1; d < 16; d <<= 1)
      for (int r = 0; r < 4; ++r) pmax[r] = fmaxf(pmax[r], __shfl_xor(pmax[r], d));
    for (int r = 0; r < 4; ++r) {
      float mn = fmaxf(m[r], pmax[r]);
      float alpha = __expf(m[r] - mn);
      m[r] = mn;
      float s = 0.0f;
      for (int c = 0; c < 4; ++c) {
        float p = __expf(pvv[c][r] - mn);
        pvv[c][r] = p;
        s += p;
      }
      rsum[r] = s;
      l[r] *= alpha;
      for (int db = 0; db < 8; ++db) accO[db][r] *= alpha;
    }
    for (int d = 1; d < 16; d <<= 1)
      for (int r = 0; r < 4; ++r) rsum[r] += __shfl_xor(rsum[r], d);
    for (int r = 0; r < 4; ++r) l[r] += rsum[r];
    for (int c = 0; c < 4; ++c)
      for (int r = 0; r < 4; ++r)
        Ps[wave][l4 * 4 + r][c * 16 + l15] = f2bf(pvv[c][r]);
    for (int kk = 0; kk < 2; ++kk) {
      bf16x8 pa = *(const bf16x8*)&Ps[wave][l15][kk * 32 + l4 * 8];
      for (int db = 0; db < 8; ++db) {
        bf16x8 vb = *(const bf16x8*)&Vt[db * 16 + l15][kk * 32 + l4 * 8];
        accO[db] = __builtin_amdgcn_mfma_f32_16x16x32_bf16(pa, vb, accO[db], 0, 0, 0);
      }
    }
    __syncthreads();
  }
  for (int db = 0; db < 8; ++db)
    for (int r = 0; r < 4; ++r) {
      int q = q0 + wave * 16 + l4 * 4 + r;
      int col = h * HD + db * 16 + l15;
      AO[((size_t)(b * SEQ) + q) * HIDDEN + col] = f2bf(accO[db][r] / l[r]);
    }
}

// ---------------------------------------------------------------------------
extern "C" void kernel_launch(void* const* d_in, const int* in_sizes, int n_in,
                              void* d_out, int out_size, void* d_ws, size_t ws_size,
                              hipStream_t stream) {
  (void)in_sizes; (void)n_in; (void)out_size; (void)ws_size;
  const float* X   = (const float*)d_in[0];
  const int*   pos = (const int*)d_in[2];
  const float* Wq  = (const float*)d_in[3];
  const float* Wk  = (const float*)d_in[4];
  const float* Wv  = (const float*)d_in[5];
  const float* Wo  = (const float*)d_in[6];

  char* ws = (char*)d_ws;
  ushort* Xb   = (ushort*)(ws);                     // 33,554,432 B  (aliased by AO later)
  ushort* Qraw = (ushort*)(ws + 33554432);          // 33,554,432 B
  ushort* Kraw = (ushort*)(ws + 67108864);          //  8,388,608 B
  ushort* Vraw = (ushort*)(ws + 75497472);          //  8,388,608 B
  ushort* WqT  = (ushort*)(ws + 83886080);          // 33,554,432 B
  ushort* WkT  = (ushort*)(ws + 117440512);         //  8,388,608 B
  ushort* WvT  = (ushort*)(ws + 125829120);         //  8,388,608 B
  ushort* WoT  = (ushort*)(ws + 134217728);         // 33,554,432 B
  ushort* AO   = Xb;                                // X dead after projections

  const int M = BSZ * SEQ;  // 4096
  dim3 blk(256);

  // ---- pre-passes: convert / transpose to bf16 ----
  cvt_bf16_kernel<<<dim3((M * HIDDEN / 8 + 255) / 256), blk, 0, stream>>>(X, Xb, M * HIDDEN / 8);
  transpose_bf16_kernel<<<dim3(HIDDEN / 32, HIDDEN / 32), blk, 0, stream>>>(Wq, WqT, HIDDEN, HIDDEN);
  transpose_bf16_kernel<<<dim3((NKV * HD) / 32, HIDDEN / 32), blk, 0, stream>>>(Wk, WkT, HIDDEN, NKV * HD);
  transpose_bf16_kernel<<<dim3((NKV * HD) / 32, HIDDEN / 32), blk, 0, stream>>>(Wv, WvT, HIDDEN, NKV * HD);
  transpose_bf16_kernel<<<dim3(HIDDEN / 32, HIDDEN / 32), blk, 0, stream>>>(Wo, WoT, HIDDEN, HIDDEN);

  // ---- projections ----
  gemm_bf16_kernel<1><<<dim3(HIDDEN / 128, M / 128), blk, 0, stream>>>(Xb, WqT, Qraw, M, HIDDEN, HIDDEN);
  gemm_bf16_kernel<1><<<dim3((NKV * HD) / 128, M / 128), blk, 0, stream>>>(Xb, WkT, Kraw, M, NKV * HD, HIDDEN);
  gemm_bf16_kernel<1><<<dim3((NKV * HD) / 128, M / 128), blk, 0, stream>>>(Xb, WvT, Vraw, M, NKV * HD, HIDDEN);

  // ---- RoPE in place ----
  rope_kernel<<<dim3((M * NH * 64) / 256), blk, 0, stream>>>(Qraw, pos, NH, M * NH * 64);
  rope_kernel<<<dim3((M * NKV * 64) / 256), blk, 0, stream>>>(Kraw, pos, NKV, M * NKV * 64);

  // ---- flash attention ----
  attn_kernel<<<dim3(SEQ / 64, NH, BSZ), blk, 0, stream>>>(Qraw, Kraw, Vraw, AO);

  // ---- output projection -> fp32 d_out ----
  gemm_bf16_kernel<0><<<dim3(HIDDEN / 128, M / 128), blk, 0, stream>>>(AO, WoT, d_out, M, HIDDEN, HIDDEN);
}

// Round 3
// 881.858 us; speedup vs baseline: 5.0463x; 1.3863x over previous
//
#include <hip/hip_runtime.h>
#include <hip/hip_bf16.h>
#include <cstdint>

#define HIDDEN 4096
#define NH 32
#define NKV 8
#define HD 128
#define SEQ 2048
#define BSZ 2

using bf16x8 = __attribute__((ext_vector_type(8))) short;
using f32x4  = __attribute__((ext_vector_type(4))) float;

__device__ __forceinline__ ushort f2bf(float f) {
  union { float f; uint32_t u; } v; v.f = f;
  uint32_t r = (v.u + 0x7FFFu + ((v.u >> 16) & 1u)) >> 16;  // RNE
  return (ushort)r;
}
__device__ __forceinline__ float bf2f(ushort s) {
  union { uint32_t u; float f; } v; v.u = ((uint32_t)s) << 16;
  return v.f;
}

__device__ __forceinline__ void gload_lds16(const void* g, void* l) {
  __builtin_amdgcn_global_load_lds(
      (const __attribute__((address_space(1))) void*)g,
      (__attribute__((address_space(3))) void*)l, 16, 0, 0);
}

// ---------------------------------------------------------------------------
// fp32 -> bf16 elementwise convert (vectorized, 8 elems/thread)
// ---------------------------------------------------------------------------
__global__ __launch_bounds__(256)
void cvt_bf16_kernel(const float* __restrict__ X, ushort* __restrict__ Xb, int n8) {
  int t = blockIdx.x * 256 + threadIdx.x;
  if (t >= n8) return;
  size_t i = (size_t)t * 8;
  float4 a = *(const float4*)(X + i);
  float4 b = *(const float4*)(X + i + 4);
  uint4 p;
  p.x = (uint)f2bf(a.x) | ((uint)f2bf(a.y) << 16);
  p.y = (uint)f2bf(a.z) | ((uint)f2bf(a.w) << 16);
  p.z = (uint)f2bf(b.x) | ((uint)f2bf(b.y) << 16);
  p.w = (uint)f2bf(b.z) | ((uint)f2bf(b.w) << 16);
  *(uint4*)(Xb + i) = p;
}

// ---------------------------------------------------------------------------
// W[K][N] fp32 -> WT[N][K] bf16 (32x32 LDS tile transpose)
// ---------------------------------------------------------------------------
__global__ __launch_bounds__(256)
void transpose_bf16_kernel(const float* __restrict__ W, ushort* __restrict__ WT,
                           int K, int N) {
  __shared__ ushort tile[32][33];
  const int k0 = blockIdx.y * 32, n0 = blockIdx.x * 32;
  const int tx = threadIdx.x & 31, ty = threadIdx.x >> 5;  // ty 0..7
  for (int i = 0; i < 4; ++i) {
    int k = ty + i * 8;
    tile[k][tx] = f2bf(W[(size_t)(k0 + k) * N + n0 + tx]);
  }
  __syncthreads();
  for (int i = 0; i < 4; ++i) {
    int n = ty + i * 8;
    WT[(size_t)(n0 + n) * K + k0 + tx] = tile[tx][n];
  }
}

// ---------------------------------------------------------------------------
// GEMM (m97 structure): C[MxN] = A[MxK] * BT[NxK]^T, A/BT bf16 row-major.
// ---------------------------------------------------------------------------
template<int OUT_BF16>
__global__ __launch_bounds__(256)
void gemm_bf16_kernel(const ushort* __restrict__ A, const ushort* __restrict__ BT,
                      void* __restrict__ Cp, int M, int N, int K) {
  __shared__ ushort As[128 * 64];
  __shared__ ushort Bs[128 * 64];
  const int tid = threadIdx.x;
  const int lane = tid & 63, wave = tid >> 6;
  const int l15 = lane & 15, l4 = lane >> 4;
  const int wr = (wave >> 1) * 64, wc = (wave & 1) * 64;
  const int m0 = blockIdx.y * 128, n0 = blockIdx.x * 128;

  const int srow = lane >> 3;
  const int scol = (lane & 7) * 8;

  f32x4 acc[4][4] = {};

  for (int k0 = 0; k0 < K; k0 += 64) {
#pragma unroll
    for (int c = 0; c < 4; ++c) {
      const int chunk = wave * 4 + c;
      const int row = chunk * 8 + srow;
      gload_lds16(A  + (size_t)(m0 + row) * K + k0 + scol, &As[chunk * 512 + lane * 8]);
      gload_lds16(BT + (size_t)(n0 + row) * K + k0 + scol, &Bs[chunk * 512 + lane * 8]);
    }
    __syncthreads();
#pragma unroll
    for (int kk = 0; kk < 2; ++kk) {
      const int ko = kk * 32 + l4 * 8;
      bf16x8 a[4], b[4];
#pragma unroll
      for (int mi = 0; mi < 4; ++mi)
        a[mi] = *(const bf16x8*)&As[(wr + mi * 16 + l15) * 64 + ko];
#pragma unroll
      for (int ni = 0; ni < 4; ++ni)
        b[ni] = *(const bf16x8*)&Bs[(wc + ni * 16 + l15) * 64 + ko];
#pragma unroll
      for (int mi = 0; mi < 4; ++mi)
#pragma unroll
        for (int ni = 0; ni < 4; ++ni)
          acc[mi][ni] = __builtin_amdgcn_mfma_f32_16x16x32_bf16(a[mi], b[ni], acc[mi][ni], 0, 0, 0);
    }
    __syncthreads();
  }
#pragma unroll
  for (int mi = 0; mi < 4; ++mi)
#pragma unroll
    for (int ni = 0; ni < 4; ++ni)
#pragma unroll
      for (int r = 0; r < 4; ++r) {
        int row = m0 + wr + mi * 16 + l4 * 4 + r;
        int col = n0 + wc + ni * 16 + l15;
        float val = acc[mi][ni][r];
        if (OUT_BF16) ((ushort*)Cp)[(size_t)row * N + col] = f2bf(val);
        else          ((float*)Cp)[(size_t)row * N + col]  = val;
      }
}

// ---------------------------------------------------------------------------
// RoPE in place on bf16 buffer laid out (b, s, nh*128).
// ---------------------------------------------------------------------------
__global__ __launch_bounds__(256)
void rope_kernel(ushort* buf, const int* __restrict__ pos_ids, int nh, int total) {
  int t = blockIdx.x * 256 + threadIdx.x;
  if (t >= total) return;
  int j = t & 63;
  int rest = t >> 6;
  int h = rest % nh;
  int bs = rest / nh;
  float pos = (float)pos_ids[bs];
  float inv = exp2f(-(float)j * (13.287712379549449f / 64.0f));
  float ang = pos * inv;
  float c = cosf(ang), s = sinf(ang);
  ushort* p = buf + ((size_t)bs * nh + h) * HD + j;
  float x1 = bf2f(p[0]), x2 = bf2f(p[64]);
  p[0]  = f2bf(x1 * c - x2 * s);
  p[64] = f2bf(x2 * c + x1 * s);
}

// ---------------------------------------------------------------------------
// Flash attention, causal, GQA-shared K/V.
// Block = (32 q-rows) x (one KV group = 4 heads); wave w handles head kh*4+w.
// K tile [64][128] staged via global_load_lds with XOR-swizzled source.
// V tile transposed to Vs[d][k], XOR-swizzled, conflict-free both sides.
// ---------------------------------------------------------------------------
__global__ __launch_bounds__(256)
void attn_kernel(const ushort* __restrict__ Q, const ushort* __restrict__ K,
                 const ushort* __restrict__ V, ushort* __restrict__ AO) {
  __shared__ ushort Ks[64 * 128];     // [k][d], chunk^=(k&7) swizzled, 16KB
  __shared__ ushort Vs[128 * 64];     // [d][k], chunk^=(d&7) swizzled, 16KB
  __shared__ ushort Ps[4][32 * 72];   // per-wave P tile 32x64, pad 72

  const int raw  = blockIdx.x;
  const int kh   = raw & 7;           // id%8 = kh -> one KV head per XCD (L2-resident K/V)
  const int rest = raw >> 3;
  const int qt   = 63 - (rest & 63);  // longest blocks dispatched first (LPT)
  const int b    = rest >> 6;
  const int q0   = qt * 32;

  const int tid = threadIdx.x, lane = tid & 63, wave = tid >> 6;
  const int l15 = lane & 15, l4 = lane >> 4;
  const int h = kh * 4 + wave;
  const float scale = 0.08838834764831845f;  // 1/sqrt(128)

  const size_t bS = (size_t)b * SEQ;
  const ushort* Kb = K + (bS * (NKV * HD)) + kh * HD;
  const ushort* Vb = V + (bS * (NKV * HD)) + kh * HD;

  // ---- Q fragments: 32 rows x 128 d per wave ----
  bf16x8 qf[2][4];
#pragma unroll
  for (int mi = 0; mi < 2; ++mi) {
    const ushort* qp = Q + (bS + q0 + mi * 16 + l15) * HIDDEN + h * HD + l4 * 8;
#pragma unroll
    for (int kk = 0; kk < 4; ++kk) qf[mi][kk] = *(const bf16x8*)(qp + kk * 32);
  }

  float mrow[2][4], denom[2][4];
#pragma unroll
  for (int mi = 0; mi < 2; ++mi)
#pragma unroll
    for (int r = 0; r < 4; ++r) { mrow[mi][r] = -1e30f; denom[mi][r] = 0.0f; }
  f32x4 accO[2][8] = {};

  const int nt = qt / 2 + 1;  // causal: k-tiles of 64 covering k <= q0+31
  for (int t = 0; t < nt; ++t) {
    const int k0 = t * 64;
    const bool mask_tile = (t == nt - 1);

    // ---- stage K tile via global_load_lds, source pre-swizzled ----
#pragma unroll
    for (int c = 0; c < 4; ++c) {
      const int j = wave * 4 + c;              // chunk 0..15 (1KB each)
      const int row = j * 4 + l4;              // 0..63
      const int chunk = (lane & 15) ^ (row & 7);
      gload_lds16(Kb + (size_t)(k0 + row) * (NKV * HD) + chunk * 8,
                  &Ks[j * 512 + lane * 8]);
    }
    // ---- stage V tile transposed into Vs[d][k] (swizzled) ----
#pragma unroll
    for (int it = 0; it < 2; ++it) {
      const int u = it * 256 + tid;
      const int rp = u & 31;                   // k-pair index: k = 2*rp
      const int dc = u >> 5;                   // d-chunk 0..15
      const ushort* vp = Vb + (size_t)(k0 + 2 * rp) * (NKV * HD) + dc * 8;
      bf16x8 lo = *(const bf16x8*)vp;
      bf16x8 hi = *(const bf16x8*)(vp + NKV * HD);
#pragma unroll
      for (int j = 0; j < 8; ++j) {
        const int d = dc * 8 + j;
        uint val = (uint)(ushort)lo[j] | ((uint)(ushort)hi[j] << 16);
        *(uint*)&Vs[d * 64 + (((rp >> 2) ^ (d & 7)) << 3) + ((rp & 3) << 1)] = val;
      }
    }
    __syncthreads();

    // ---- QK^T: S[32 q x 64 k] per wave ----
    f32x4 accS[2][4] = {};
#pragma unroll
    for (int kk = 0; kk < 4; ++kk) {
#pragma unroll
      for (int ni = 0; ni < 4; ++ni) {
        bf16x8 kf = *(const bf16x8*)&Ks[(ni * 16 + l15) * 128 +
                                        (((kk * 4 + l4) ^ (l15 & 7)) << 3)];
        accS[0][ni] = __builtin_amdgcn_mfma_f32_16x16x32_bf16(qf[0][kk], kf, accS[0][ni], 0, 0, 0);
        accS[1][ni] = __builtin_amdgcn_mfma_f32_16x16x32_bf16(qf[1][kk], kf, accS[1][ni], 0, 0, 0);
      }
    }

    // ---- online softmax (8 rows/lane: mi x r) ----
    float pmax[2][4];
#pragma unroll
    for (int mi = 0; mi < 2; ++mi)
#pragma unroll
      for (int r = 0; r < 4; ++r) {
        float mx = -1e30f;
#pragma unroll
        for (int ni = 0; ni < 4; ++ni) {
          float x = accS[mi][ni][r] * scale;
          if (mask_tile) {
            int kq = k0 + ni * 16 + l15;
            int qq = q0 + mi * 16 + l4 * 4 + r;
            if (kq > qq) x = -1e30f;
          }
          accS[mi][ni][r] = x;
          mx = fmaxf(mx, x);
        }
        pmax[mi][r] = mx;
      }
#pragma unroll
    for (int d = 1; d < 16; d <<= 1)
#pragma unroll
      for (int mi = 0; mi < 2; ++mi)
#pragma unroll
        for (int r = 0; r < 4; ++r)
          pmax[mi][r] = fmaxf(pmax[mi][r], __shfl_xor(pmax[mi][r], d));

    float rsum[2][4];
#pragma unroll
    for (int mi = 0; mi < 2; ++mi)
#pragma unroll
      for (int r = 0; r < 4; ++r) {
        float mn = fmaxf(mrow[mi][r], pmax[mi][r]);
        float alpha = __expf(mrow[mi][r] - mn);
        mrow[mi][r] = mn;
        float s = 0.0f;
#pragma unroll
        for (int ni = 0; ni < 4; ++ni) {
          float p = __expf(accS[mi][ni][r] - mn);
          accS[mi][ni][r] = p;
          s += p;
        }
        rsum[mi][r] = s;
        denom[mi][r] *= alpha;
#pragma unroll
        for (int db = 0; db < 8; ++db) accO[mi][db][r] *= alpha;
      }
#pragma unroll
    for (int d = 1; d < 16; d <<= 1)
#pragma unroll
      for (int mi = 0; mi < 2; ++mi)
#pragma unroll
        for (int r = 0; r < 4; ++r)
          rsum[mi][r] += __shfl_xor(rsum[mi][r], d);
#pragma unroll
    for (int mi = 0; mi < 2; ++mi)
#pragma unroll
      for (int r = 0; r < 4; ++r) denom[mi][r] += rsum[mi][r];

    // ---- write P (bf16) to per-wave LDS tile ----
#pragma unroll
    for (int mi = 0; mi < 2; ++mi)
#pragma unroll
      for (int ni = 0; ni < 4; ++ni)
#pragma unroll
        for (int r = 0; r < 4; ++r)
          Ps[wave][(mi * 16 + l4 * 4 + r) * 72 + ni * 16 + l15] = f2bf(accS[mi][ni][r]);

    // ---- PV: O += P(32x64) * V(64x128) ----
#pragma unroll
    for (int kk = 0; kk < 2; ++kk) {
      bf16x8 pa[2];
#pragma unroll
      for (int mi = 0; mi < 2; ++mi)
        pa[mi] = *(const bf16x8*)&Ps[wave][(mi * 16 + l15) * 72 + kk * 32 + l4 * 8];
#pragma unroll
      for (int db = 0; db < 8; ++db) {
        bf16x8 vb = *(const bf16x8*)&Vs[(db * 16 + l15) * 64 +
                                        (((kk * 4 + l4) ^ (l15 & 7)) << 3)];
        accO[0][db] = __builtin_amdgcn_mfma_f32_16x16x32_bf16(pa[0], vb, accO[0][db], 0, 0, 0);
        accO[1][db] = __builtin_amdgcn_mfma_f32_16x16x32_bf16(pa[1], vb, accO[1][db], 0, 0, 0);
      }
    }
    __syncthreads();
  }

  // ---- epilogue ----
#pragma unroll
  for (int mi = 0; mi < 2; ++mi)
#pragma unroll
    for (int db = 0; db < 8; ++db)
#pragma unroll
      for (int r = 0; r < 4; ++r) {
        int q = q0 + mi * 16 + l4 * 4 + r;
        int col = h * HD + db * 16 + l15;
        AO[(bS + q) * HIDDEN + col] = f2bf(accO[mi][db][r] / denom[mi][r]);
      }
}

// ---------------------------------------------------------------------------
extern "C" void kernel_launch(void* const* d_in, const int* in_sizes, int n_in,
                              void* d_out, int out_size, void* d_ws, size_t ws_size,
                              hipStream_t stream) {
  (void)in_sizes; (void)n_in; (void)out_size; (void)ws_size;
  const float* X   = (const float*)d_in[0];
  const int*   pos = (const int*)d_in[2];
  const float* Wq  = (const float*)d_in[3];
  const float* Wk  = (const float*)d_in[4];
  const float* Wv  = (const float*)d_in[5];
  const float* Wo  = (const float*)d_in[6];

  char* ws = (char*)d_ws;
  ushort* Xb   = (ushort*)(ws);
  ushort* Qraw = (ushort*)(ws + 33554432);
  ushort* Kraw = (ushort*)(ws + 67108864);
  ushort* Vraw = (ushort*)(ws + 75497472);
  ushort* WqT  = (ushort*)(ws + 83886080);
  ushort* WkT  = (ushort*)(ws + 117440512);
  ushort* WvT  = (ushort*)(ws + 125829120);
  ushort* WoT  = (ushort*)(ws + 134217728);
  ushort* AO   = Xb;  // X dead after projections

  const int M = BSZ * SEQ;  // 4096
  dim3 blk(256);

  cvt_bf16_kernel<<<dim3((M * HIDDEN / 8 + 255) / 256), blk, 0, stream>>>(X, Xb, M * HIDDEN / 8);
  transpose_bf16_kernel<<<dim3(HIDDEN / 32, HIDDEN / 32), blk, 0, stream>>>(Wq, WqT, HIDDEN, HIDDEN);
  transpose_bf16_kernel<<<dim3((NKV * HD) / 32, HIDDEN / 32), blk, 0, stream>>>(Wk, WkT, HIDDEN, NKV * HD);
  transpose_bf16_kernel<<<dim3((NKV * HD) / 32, HIDDEN / 32), blk, 0, stream>>>(Wv, WvT, HIDDEN, NKV * HD);
  transpose_bf16_kernel<<<dim3(HIDDEN / 32, HIDDEN / 32), blk, 0, stream>>>(Wo, WoT, HIDDEN, HIDDEN);

  gemm_bf16_kernel<1><<<dim3(HIDDEN / 128, M / 128), blk, 0, stream>>>(Xb, WqT, Qraw, M, HIDDEN, HIDDEN);
  gemm_bf16_kernel<1><<<dim3((NKV * HD) / 128, M / 128), blk, 0, stream>>>(Xb, WkT, Kraw, M, NKV * HD, HIDDEN);
  gemm_bf16_kernel<1><<<dim3((NKV * HD) / 128, M / 128), blk, 0, stream>>>(Xb, WvT, Vraw, M, NKV * HD, HIDDEN);

  rope_kernel<<<dim3((M * NH * 64) / 256), blk, 0, stream>>>(Qraw, pos, NH, M * NH * 64);
  rope_kernel<<<dim3((M * NKV * 64) / 256), blk, 0, stream>>>(Kraw, pos, NKV, M * NKV * 64);

  // flash attention: grid = 8 kv-heads (low bits -> XCD) x 64 q-tiles x 2 batch
  attn_kernel<<<dim3(8 * 64 * BSZ), blk, 0, stream>>>(Qraw, Kraw, Vraw, AO);

  gemm_bf16_kernel<0><<<dim3(HIDDEN / 128, M / 128), blk, 0, stream>>>(AO, WoT, d_out, M, HIDDEN, HIDDEN);
}

// Round 4
// 828.942 us; speedup vs baseline: 5.3684x; 1.0638x over previous
//
#include <hip/hip_runtime.h>
#include <hip/hip_bf16.h>
#include <cstdint>

#define HIDDEN 4096
#define NH 32
#define NKV 8
#define HD 128
#define SEQ 2048
#define BSZ 2
#define QKVN 6144          // fused QKV projection width
#define QKVLD 6144         // row stride of fused QKV buffer

using bf16x8 = __attribute__((ext_vector_type(8))) short;
using f32x4  = __attribute__((ext_vector_type(4))) float;

__device__ __forceinline__ ushort f2bf(float f) {
  union { float f; uint32_t u; } v; v.f = f;
  uint32_t r = (v.u + 0x7FFFu + ((v.u >> 16) & 1u)) >> 16;  // RNE
  return (ushort)r;
}
__device__ __forceinline__ float bf2f(ushort s) {
  union { uint32_t u; float f; } v; v.u = ((uint32_t)s) << 16;
  return v.f;
}

__device__ __forceinline__ void gload_lds16(const void* g, void* l) {
  __builtin_amdgcn_global_load_lds(
      (const __attribute__((address_space(1))) void*)g,
      (__attribute__((address_space(3))) void*)l, 16, 0, 0);
}

// ---------------------------------------------------------------------------
// fp32 -> bf16 elementwise convert (vectorized, 8 elems/thread)
// ---------------------------------------------------------------------------
__global__ __launch_bounds__(256)
void cvt_bf16_kernel(const float* __restrict__ X, ushort* __restrict__ Xb, int n8) {
  int t = blockIdx.x * 256 + threadIdx.x;
  if (t >= n8) return;
  size_t i = (size_t)t * 8;
  float4 a = *(const float4*)(X + i);
  float4 b = *(const float4*)(X + i + 4);
  uint4 p;
  p.x = (uint)f2bf(a.x) | ((uint)f2bf(a.y) << 16);
  p.y = (uint)f2bf(a.z) | ((uint)f2bf(a.w) << 16);
  p.z = (uint)f2bf(b.x) | ((uint)f2bf(b.y) << 16);
  p.w = (uint)f2bf(b.z) | ((uint)f2bf(b.w) << 16);
  *(uint4*)(Xb + i) = p;
}

// ---------------------------------------------------------------------------
// W[K][N] fp32 -> WT[N][K] bf16 (32x32 LDS tile transpose)
// ---------------------------------------------------------------------------
__global__ __launch_bounds__(256)
void transpose_bf16_kernel(const float* __restrict__ W, ushort* __restrict__ WT,
                           int K, int N) {
  __shared__ ushort tile[32][33];
  const int k0 = blockIdx.y * 32, n0 = blockIdx.x * 32;
  const int tx = threadIdx.x & 31, ty = threadIdx.x >> 5;  // ty 0..7
  for (int i = 0; i < 4; ++i) {
    int k = ty + i * 8;
    tile[k][tx] = f2bf(W[(size_t)(k0 + k) * N + n0 + tx]);
  }
  __syncthreads();
  for (int i = 0; i < 4; ++i) {
    int n = ty + i * 8;
    WT[(size_t)(n0 + n) * K + k0 + tx] = tile[tx][n];
  }
}

// ---------------------------------------------------------------------------
// GEMM (m97 structure): C[MxN] = A[MxK] * BT[NxK]^T, A/BT bf16 row-major.
// ---------------------------------------------------------------------------
template<int OUT_BF16>
__global__ __launch_bounds__(256)
void gemm_bf16_kernel(const ushort* __restrict__ A, const ushort* __restrict__ BT,
                      void* __restrict__ Cp, int M, int N, int K) {
  __shared__ ushort As[128 * 64];
  __shared__ ushort Bs[128 * 64];
  const int tid = threadIdx.x;
  const int lane = tid & 63, wave = tid >> 6;
  const int l15 = lane & 15, l4 = lane >> 4;
  const int wr = (wave >> 1) * 64, wc = (wave & 1) * 64;
  const int m0 = blockIdx.y * 128, n0 = blockIdx.x * 128;

  const int srow = lane >> 3;
  const int scol = (lane & 7) * 8;

  f32x4 acc[4][4] = {};

  for (int k0 = 0; k0 < K; k0 += 64) {
#pragma unroll
    for (int c = 0; c < 4; ++c) {
      const int chunk = wave * 4 + c;
      const int row = chunk * 8 + srow;
      gload_lds16(A  + (size_t)(m0 + row) * K + k0 + scol, &As[chunk * 512 + lane * 8]);
      gload_lds16(BT + (size_t)(n0 + row) * K + k0 + scol, &Bs[chunk * 512 + lane * 8]);
    }
    __syncthreads();
#pragma unroll
    for (int kk = 0; kk < 2; ++kk) {
      const int ko = kk * 32 + l4 * 8;
      bf16x8 a[4], b[4];
#pragma unroll
      for (int mi = 0; mi < 4; ++mi)
        a[mi] = *(const bf16x8*)&As[(wr + mi * 16 + l15) * 64 + ko];
#pragma unroll
      for (int ni = 0; ni < 4; ++ni)
        b[ni] = *(const bf16x8*)&Bs[(wc + ni * 16 + l15) * 64 + ko];
#pragma unroll
      for (int mi = 0; mi < 4; ++mi)
#pragma unroll
        for (int ni = 0; ni < 4; ++ni)
          acc[mi][ni] = __builtin_amdgcn_mfma_f32_16x16x32_bf16(a[mi], b[ni], acc[mi][ni], 0, 0, 0);
    }
    __syncthreads();
  }
#pragma unroll
  for (int mi = 0; mi < 4; ++mi)
#pragma unroll
    for (int ni = 0; ni < 4; ++ni)
#pragma unroll
      for (int r = 0; r < 4; ++r) {
        int row = m0 + wr + mi * 16 + l4 * 4 + r;
        int col = n0 + wc + ni * 16 + l15;
        float val = acc[mi][ni][r];
        if (OUT_BF16) ((ushort*)Cp)[(size_t)row * N + col] = f2bf(val);
        else          ((float*)Cp)[(size_t)row * N + col]  = val;
      }
}

// ---------------------------------------------------------------------------
// RoPE in place on bf16 buffer: element (b,s,h,j) at buf[(b*S+s)*ld + h*HD + j]
// ---------------------------------------------------------------------------
__global__ __launch_bounds__(256)
void rope_kernel(ushort* buf, const int* __restrict__ pos_ids, int nh, int ld, int total) {
  int t = blockIdx.x * 256 + threadIdx.x;
  if (t >= total) return;
  int j = t & 63;
  int rest = t >> 6;
  int h = rest % nh;
  int bs = rest / nh;
  float pos = (float)pos_ids[bs];
  float inv = exp2f(-(float)j * (13.287712379549449f / 64.0f));
  float ang = pos * inv;
  float c = cosf(ang), s = sinf(ang);
  ushort* p = buf + (size_t)bs * ld + h * HD + j;
  float x1 = bf2f(p[0]), x2 = bf2f(p[64]);
  p[0]  = f2bf(x1 * c - x2 * s);
  p[64] = f2bf(x2 * c + x1 * s);
}

// ---------------------------------------------------------------------------
// Flash attention, causal, GQA-shared K/V, async-staged (T14), defer-max (T13).
// Block = (32 q-rows) x (one KV group = 4 heads); wave w handles head kh*4+w.
// Q/K/V live in the fused QKV buffer with row stride QKVLD.
// ---------------------------------------------------------------------------
__global__ __launch_bounds__(256)
void attn_kernel(const ushort* __restrict__ Q, const ushort* __restrict__ K0,
                 const ushort* __restrict__ V0, ushort* __restrict__ AO) {
  __shared__ ushort Ks[64 * 128];       // [k][d], chunk^=(k&7) swizzled, 16KB
  __shared__ ushort Vs[2][128 * 64];    // [d][k], chunk^=(d&7) swizzled, 2x16KB
  __shared__ ushort Ps[4][32 * 72];     // per-wave P tile 32x64, pad 72

  const int raw  = blockIdx.x;
  const int kh   = raw & 7;             // kv-head -> XCD (L2-resident K/V)
  const int rest = raw >> 3;
  const int qt   = 63 - (rest & 63);    // longest blocks first (LPT)
  const int b    = rest >> 6;
  const int q0   = qt * 32;

  const int tid = threadIdx.x, lane = tid & 63, wave = tid >> 6;
  const int l15 = lane & 15, l4 = lane >> 4;
  const int h = kh * 4 + wave;
  const float SCL2 = 0.1275173110f;     // (1/sqrt(128)) * log2(e)

  const size_t bS = (size_t)b * SEQ;
  const ushort* Kb = K0 + bS * QKVLD + kh * HD;
  const ushort* Vb = V0 + bS * QKVLD + kh * HD;

  // ---- Q fragments: 32 rows x 128 d per wave ----
  bf16x8 qf[2][4];
#pragma unroll
  for (int mi = 0; mi < 2; ++mi) {
    const ushort* qp = Q + (bS + q0 + mi * 16 + l15) * QKVLD + h * HD + l4 * 8;
#pragma unroll
    for (int kk = 0; kk < 4; ++kk) qf[mi][kk] = *(const bf16x8*)(qp + kk * 32);
  }

  float mrow[2][4], denom[2][4];
#pragma unroll
  for (int mi = 0; mi < 2; ++mi)
#pragma unroll
    for (int r = 0; r < 4; ++r) { mrow[mi][r] = -1e30f; denom[mi][r] = 0.0f; }
  f32x4 accO[2][8] = {};

  // staging geometry
  const int krow  = (wave * 4) * 4 + l4;            // varies with c below
  (void)krow;
  const int rp0 = tid & 31,        dc0 = tid >> 5;            // V chunk for u=tid
  const int rp1 = (256 + tid) & 31, dc1 = (256 + tid) >> 5;   // V chunk for u=256+tid

  const int nt = qt / 2 + 1;  // causal coverage

  // ---- prologue: stage K(0) and V(0) ----
  {
#pragma unroll
    for (int c = 0; c < 4; ++c) {
      const int j = wave * 4 + c;
      const int row = j * 4 + l4;
      const int chunk = (lane & 15) ^ (row & 7);
      gload_lds16(Kb + (size_t)row * QKVLD + chunk * 8, &Ks[j * 512 + lane * 8]);
    }
    const ushort* vp0 = Vb + (size_t)(2 * rp0) * QKVLD + dc0 * 8;
    const ushort* vp1 = Vb + (size_t)(2 * rp1) * QKVLD + dc1 * 8;
    bf16x8 lo0 = *(const bf16x8*)vp0, hi0 = *(const bf16x8*)(vp0 + QKVLD);
    bf16x8 lo1 = *(const bf16x8*)vp1, hi1 = *(const bf16x8*)(vp1 + QKVLD);
#pragma unroll
    for (int j = 0; j < 8; ++j) {
      const int d0 = dc0 * 8 + j, d1 = dc1 * 8 + j;
      uint v0p = (uint)(ushort)lo0[j] | ((uint)(ushort)hi0[j] << 16);
      uint v1p = (uint)(ushort)lo1[j] | ((uint)(ushort)hi1[j] << 16);
      *(uint*)&Vs[0][d0 * 64 + (((rp0 >> 2) ^ (d0 & 7)) << 3) + ((rp0 & 3) << 1)] = v0p;
      *(uint*)&Vs[0][d1 * 64 + (((rp1 >> 2) ^ (d1 & 7)) << 3) + ((rp1 & 3) << 1)] = v1p;
    }
  }
  __syncthreads();

  for (int t = 0; t < nt; ++t) {
    const int k0 = t * 64;
    const int cur = t & 1;
    const bool mask_tile = (t == nt - 1);
    const bool pf = (t + 1 < nt);

    // ---- QK^T: S[32 q x 64 k] per wave, from Ks ----
    f32x4 accS[2][4] = {};
    __builtin_amdgcn_s_setprio(1);
#pragma unroll
    for (int kk = 0; kk < 4; ++kk) {
#pragma unroll
      for (int ni = 0; ni < 4; ++ni) {
        bf16x8 kf = *(const bf16x8*)&Ks[(ni * 16 + l15) * 128 +
                                        (((kk * 4 + l4) ^ (l15 & 7)) << 3)];
        accS[0][ni] = __builtin_amdgcn_mfma_f32_16x16x32_bf16(qf[0][kk], kf, accS[0][ni], 0, 0, 0);
        accS[1][ni] = __builtin_amdgcn_mfma_f32_16x16x32_bf16(qf[1][kk], kf, accS[1][ni], 0, 0, 0);
      }
    }
    __builtin_amdgcn_s_setprio(0);
    __syncthreads();   // all waves done reading Ks -> safe to overwrite

    // ---- issue next tile's loads (latency hides under softmax+PV) ----
    bf16x8 lo0, hi0, lo1, hi1;
    if (pf) {
      const int kn = k0 + 64;
#pragma unroll
      for (int c = 0; c < 4; ++c) {
        const int j = wave * 4 + c;
        const int row = j * 4 + l4;
        const int chunk = (lane & 15) ^ (row & 7);
        gload_lds16(Kb + (size_t)(kn + row) * QKVLD + chunk * 8, &Ks[j * 512 + lane * 8]);
      }
      const ushort* vp0 = Vb + (size_t)(kn + 2 * rp0) * QKVLD + dc0 * 8;
      const ushort* vp1 = Vb + (size_t)(kn + 2 * rp1) * QKVLD + dc1 * 8;
      lo0 = *(const bf16x8*)vp0; hi0 = *(const bf16x8*)(vp0 + QKVLD);
      lo1 = *(const bf16x8*)vp1; hi1 = *(const bf16x8*)(vp1 + QKVLD);
    }

    // ---- softmax (defer-max, per-lane partial denom) ----
    float pmax[2][4];
#pragma unroll
    for (int mi = 0; mi < 2; ++mi)
#pragma unroll
      for (int r = 0; r < 4; ++r) {
        float mx = -3e38f;
#pragma unroll
        for (int ni = 0; ni < 4; ++ni) {
          float x = accS[mi][ni][r] * SCL2;
          if (mask_tile) {
            int kq = k0 + ni * 16 + l15;
            int qq = q0 + mi * 16 + l4 * 4 + r;
            if (kq > qq) x = -1e30f;
          }
          accS[mi][ni][r] = x;
          mx = fmaxf(mx, x);
        }
        pmax[mi][r] = mx;
      }
#pragma unroll
    for (int d = 1; d < 16; d <<= 1)
#pragma unroll
      for (int mi = 0; mi < 2; ++mi)
#pragma unroll
        for (int r = 0; r < 4; ++r)
          pmax[mi][r] = fmaxf(pmax[mi][r], __shfl_xor(pmax[mi][r], d));

    bool ok = true;
#pragma unroll
    for (int mi = 0; mi < 2; ++mi)
#pragma unroll
      for (int r = 0; r < 4; ++r)
        ok = ok && (pmax[mi][r] - mrow[mi][r] <= 8.0f);

    if (__all(ok)) {
      // deferred: keep old max, no rescale (P bounded by 2^8)
#pragma unroll
      for (int mi = 0; mi < 2; ++mi)
#pragma unroll
        for (int r = 0; r < 4; ++r) {
          const float mn = mrow[mi][r];
          float s = 0.0f;
#pragma unroll
          for (int ni = 0; ni < 4; ++ni) {
            float p = exp2f(accS[mi][ni][r] - mn);
            accS[mi][ni][r] = p;
            s += p;
          }
          denom[mi][r] += s;
        }
    } else {
#pragma unroll
      for (int mi = 0; mi < 2; ++mi)
#pragma unroll
        for (int r = 0; r < 4; ++r) {
          const float mn = fmaxf(mrow[mi][r], pmax[mi][r]);
          const float alpha = exp2f(mrow[mi][r] - mn);
          mrow[mi][r] = mn;
          float s = 0.0f;
#pragma unroll
          for (int ni = 0; ni < 4; ++ni) {
            float p = exp2f(accS[mi][ni][r] - mn);
            accS[mi][ni][r] = p;
            s += p;
          }
          denom[mi][r] = denom[mi][r] * alpha + s;
#pragma unroll
          for (int db = 0; db < 8; ++db) accO[mi][db][r] *= alpha;
        }
    }

    // ---- write P (bf16) to per-wave LDS tile ----
#pragma unroll
    for (int mi = 0; mi < 2; ++mi)
#pragma unroll
      for (int ni = 0; ni < 4; ++ni)
#pragma unroll
        for (int r = 0; r < 4; ++r)
          Ps[wave][(mi * 16 + l4 * 4 + r) * 72 + ni * 16 + l15] = f2bf(accS[mi][ni][r]);

    // ---- PV: O += P(32x64) * V(64x128), from Vs[cur] ----
    __builtin_amdgcn_s_setprio(1);
#pragma unroll
    for (int kk = 0; kk < 2; ++kk) {
      bf16x8 pa[2];
#pragma unroll
      for (int mi = 0; mi < 2; ++mi)
        pa[mi] = *(const bf16x8*)&Ps[wave][(mi * 16 + l15) * 72 + kk * 32 + l4 * 8];
#pragma unroll
      for (int db = 0; db < 8; ++db) {
        bf16x8 vb = *(const bf16x8*)&Vs[cur][(db * 16 + l15) * 64 +
                                            (((kk * 4 + l4) ^ (l15 & 7)) << 3)];
        accO[0][db] = __builtin_amdgcn_mfma_f32_16x16x32_bf16(pa[0], vb, accO[0][db], 0, 0, 0);
        accO[1][db] = __builtin_amdgcn_mfma_f32_16x16x32_bf16(pa[1], vb, accO[1][db], 0, 0, 0);
      }
    }
    __builtin_amdgcn_s_setprio(0);

    // ---- write V(t+1) into the other buffer (data-dep waits handle vmcnt) ----
    if (pf) {
#pragma unroll
      for (int j = 0; j < 8; ++j) {
        const int d0 = dc0 * 8 + j, d1 = dc1 * 8 + j;
        uint v0p = (uint)(ushort)lo0[j] | ((uint)(ushort)hi0[j] << 16);
        uint v1p = (uint)(ushort)lo1[j] | ((uint)(ushort)hi1[j] << 16);
        *(uint*)&Vs[cur ^ 1][d0 * 64 + (((rp0 >> 2) ^ (d0 & 7)) << 3) + ((rp0 & 3) << 1)] = v0p;
        *(uint*)&Vs[cur ^ 1][d1 * 64 + (((rp1 >> 2) ^ (d1 & 7)) << 3) + ((rp1 & 3) << 1)] = v1p;
      }
    }
    __syncthreads();
  }

  // ---- epilogue: reduce denom across l15, divide, store ----
#pragma unroll
  for (int d = 1; d < 16; d <<= 1)
#pragma unroll
    for (int mi = 0; mi < 2; ++mi)
#pragma unroll
      for (int r = 0; r < 4; ++r)
        denom[mi][r] += __shfl_xor(denom[mi][r], d);

#pragma unroll
  for (int mi = 0; mi < 2; ++mi)
#pragma unroll
    for (int db = 0; db < 8; ++db)
#pragma unroll
      for (int r = 0; r < 4; ++r) {
        int q = q0 + mi * 16 + l4 * 4 + r;
        int col = h * HD + db * 16 + l15;
        AO[(bS + q) * HIDDEN + col] = f2bf(accO[mi][db][r] / denom[mi][r]);
      }
}

// ---------------------------------------------------------------------------
extern "C" void kernel_launch(void* const* d_in, const int* in_sizes, int n_in,
                              void* d_out, int out_size, void* d_ws, size_t ws_size,
                              hipStream_t stream) {
  (void)in_sizes; (void)n_in; (void)out_size; (void)ws_size;
  const float* X   = (const float*)d_in[0];
  const int*   pos = (const int*)d_in[2];
  const float* Wq  = (const float*)d_in[3];
  const float* Wk  = (const float*)d_in[4];
  const float* Wv  = (const float*)d_in[5];
  const float* Wo  = (const float*)d_in[6];

  char* ws = (char*)d_ws;
  ushort* Xb    = (ushort*)(ws);                    // 33,554,432 B (aliased by AO)
  ushort* QKV   = (ushort*)(ws + 33554432);         // 50,331,648 B  [M][6144]
  ushort* BTqkv = (ushort*)(ws + 83886080);         // 50,331,648 B  [6144][4096]
  ushort* WoT   = (ushort*)(ws + 134217728);        // 33,554,432 B
  ushort* AO    = Xb;                               // X dead after QKV projection

  const int M = BSZ * SEQ;  // 4096
  dim3 blk(256);

  // ---- pre-passes ----
  cvt_bf16_kernel<<<dim3((M * HIDDEN / 8 + 255) / 256), blk, 0, stream>>>(X, Xb, M * HIDDEN / 8);
  transpose_bf16_kernel<<<dim3(HIDDEN / 32, HIDDEN / 32), blk, 0, stream>>>(Wq, BTqkv, HIDDEN, HIDDEN);
  transpose_bf16_kernel<<<dim3((NKV * HD) / 32, HIDDEN / 32), blk, 0, stream>>>(
      Wk, BTqkv + (size_t)HIDDEN * HIDDEN, HIDDEN, NKV * HD);
  transpose_bf16_kernel<<<dim3((NKV * HD) / 32, HIDDEN / 32), blk, 0, stream>>>(
      Wv, BTqkv + (size_t)(HIDDEN + NKV * HD) * HIDDEN, HIDDEN, NKV * HD);
  transpose_bf16_kernel<<<dim3(HIDDEN / 32, HIDDEN / 32), blk, 0, stream>>>(Wo, WoT, HIDDEN, HIDDEN);

  // ---- fused QKV projection: [M][4096] x [4096][6144] -> [M][6144] ----
  gemm_bf16_kernel<1><<<dim3(QKVN / 128, M / 128), blk, 0, stream>>>(Xb, BTqkv, QKV, M, QKVN, HIDDEN);

  // ---- RoPE in place (Q cols 0..4095, K cols 4096..5119) ----
  rope_kernel<<<dim3((M * NH * 64) / 256), blk, 0, stream>>>(QKV, pos, NH, QKVLD, M * NH * 64);
  rope_kernel<<<dim3((M * NKV * 64) / 256), blk, 0, stream>>>(QKV + HIDDEN, pos, NKV, QKVLD, M * NKV * 64);

  // ---- flash attention ----
  attn_kernel<<<dim3(8 * 64 * BSZ), blk, 0, stream>>>(
      QKV, QKV + HIDDEN, QKV + HIDDEN + NKV * HD, AO);

  // ---- output projection -> fp32 d_out ----
  gemm_bf16_kernel<0><<<dim3(HIDDEN / 128, M / 128), blk, 0, stream>>>(AO, WoT, d_out, M, HIDDEN, HIDDEN);
}